// Round 11
// baseline (72.883 us; speedup 1.0000x reference)
//
#include <hip/hip_runtime.h>

// Problem constants
constexpr int NB  = 1024;
constexpr int NIN = 512;
constexpr int NJ  = 64;
constexpr int NK  = 8;
constexpr int NC  = NJ * NK;          // 512
constexpr int OUTC = NIN + NJ;        // 576
constexpr float EXPN10 = 4.5399929762484854e-05f;
constexpr float FEAT_BASE = 1024.0f * EXPN10;

typedef __bf16 bf16x8 __attribute__((ext_vector_type(8)));
typedef float floatx16 __attribute__((ext_vector_type(16)));

__device__ __forceinline__ unsigned f2bf(float f) {  // RNE fp32->bf16
  unsigned u = __float_as_uint(f);
  u += 0x7FFFu + ((u >> 16) & 1u);
  return u >> 16;
}

// ---------------------------------------------------------------------------
// Kernel 1 (gemm_fused): byte-identical to R8 (best measured config, 72.1us
// total). R10's 1-phase/2-wave variant measured identical => gemm's
// phase/TLP axis exhausted; keep the proven one.
// ---------------------------------------------------------------------------
__global__ __launch_bounds__(256) void gemm_fused(const float* __restrict__ x,
                                                  const float* __restrict__ T,
                                                  float* __restrict__ Mp,
                                                  uint4* __restrict__ Mb,
                                                  float* __restrict__ na,
                                                  float* __restrict__ out) {
  __shared__ __align__(16) ushort smem_u[2 * 64 * 136 + 2 * 32 * 136];  // 52224 B
  ushort* Xs = smem_u;                     // [2][64][136] bf16 A halves
  ushort* Ts = smem_u + 2 * 64 * 136;      // [2][32][136] bf16 B halves (transposed)
  float*  Cs = (float*)smem_u;             // [2][64][36] fp32 partial tiles (overlay)

  const int tid = threadIdx.x;
  const int b0 = blockIdx.x * 64;
  const int c0 = blockIdx.y * 32;

  const int lane = tid & 63;
  const int w    = tid >> 6;
  const int l31  = lane & 31;
  const int half = lane >> 5;
  const int wr   = w & 1;        // arow half
  const int kh   = w >> 1;       // K half owned by this wave
  const int arow = wr * 32 + l31;

  // B-transpose thread mapping
  const int bk = tid >> 3;        // 0..31 : k-pair index within 64-row group
  const int bc = (tid & 7) * 4;   // 0..28 : c-quad offset

  // ---- out init (256 blocks x 576 float4) ----
  const int bidf = blockIdx.y * 16 + blockIdx.x;   // 0..255
#pragma unroll
  for (int it = 0; it < 3; ++it) {
    const int li = it * 256 + tid;
    if (li < 576) {
      const int gi = bidf * 576 + li;
      const int b = gi / (OUTC / 4);                 // /144 -> magic mul
      const int r = gi - b * (OUTC / 4);
      float4 v;
      if (r < NIN / 4) v = ((const float4*)x)[b * (NIN / 4) + r];
      else v = float4{FEAT_BASE, FEAT_BASE, FEAT_BASE, FEAT_BASE};
      ((float4*)out)[gi] = v;
    }
  }

  floatx16 acc = {};

  for (int z = 0; z < 2; ++z) {
    // ======== load phase: ALL global loads for BOTH K-halves batched ========
    float4 av[16];
#pragma unroll
    for (int kk = 0; kk < 2; ++kk) {
#pragma unroll
      for (int t = 0; t < 4; ++t) {
        const int u = t * 256 + tid;
        const int row = u >> 4, seg = u & 15;
        const size_t base = (size_t)(b0 + row) * NIN + (kk * 2 + z) * 128 + seg * 8;
        av[kk * 8 + 2 * t]     = *(const float4*)&x[base];
        av[kk * 8 + 2 * t + 1] = *(const float4*)&x[base + 4];
      }
    }
    float4 bv[8];
#pragma unroll
    for (int kk = 0; kk < 2; ++kk) {
#pragma unroll
      for (int it = 0; it < 2; ++it) {
        const int k0 = it * 64 + bk * 2;             // local k (even), 0..126
        const size_t base = (size_t)((kk * 2 + z) * 128 + k0) * NC + c0 + bc;
        bv[kk * 4 + 2 * it]     = *(const float4*)&T[base];      // row k0
        bv[kk * 4 + 2 * it + 1] = *(const float4*)&T[base + NC]; // row k0+1
      }
    }

    // ======== write phase: convert + LDS ========
#pragma unroll
    for (int kk = 0; kk < 2; ++kk) {
#pragma unroll
      for (int t = 0; t < 4; ++t) {
        const int u = t * 256 + tid;
        const int row = u >> 4, seg = u & 15;
        uint4 p;
        p.x = f2bf(av[kk * 8 + 2 * t].x) | (f2bf(av[kk * 8 + 2 * t].y) << 16);
        p.y = f2bf(av[kk * 8 + 2 * t].z) | (f2bf(av[kk * 8 + 2 * t].w) << 16);
        p.z = f2bf(av[kk * 8 + 2 * t + 1].x) | (f2bf(av[kk * 8 + 2 * t + 1].y) << 16);
        p.w = f2bf(av[kk * 8 + 2 * t + 1].z) | (f2bf(av[kk * 8 + 2 * t + 1].w) << 16);
        *(uint4*)&Xs[kk * 64 * 136 + row * 136 + seg * 8] = p;
      }
      unsigned* Tw = (unsigned*)(Ts + kk * 32 * 136);   // dword view, row stride 68
#pragma unroll
      for (int it = 0; it < 2; ++it) {
        const float* lo = &bv[kk * 4 + 2 * it].x;
        const float* hi = &bv[kk * 4 + 2 * it + 1].x;
#pragma unroll
        for (int q = 0; q < 4; ++q) {
          const unsigned val = f2bf(lo[q]) | (f2bf(hi[q]) << 16);
          Tw[(bc + q) * 68 + it * 32 + bk] = val;      // Ts[kk][c][k0..k0+1]
        }
      }
    }

    __syncthreads();

    // ---- MFMA: 8 steps of K=16 on this wave's K-half ----
#pragma unroll
    for (int s = 0; s < 8; ++s) {
      const bf16x8 af = *(const bf16x8*)&Xs[kh * 64 * 136 + arow * 136 + s * 16 + half * 8];
      const bf16x8 bf = *(const bf16x8*)&Ts[kh * 32 * 136 + l31 * 136 + s * 16 + half * 8];
      acc = __builtin_amdgcn_mfma_f32_32x32x16_bf16(af, bf, acc, 0, 0, 0);
    }
    __syncthreads();
  }

  // ---- epilogue: partials -> Cs[kh], sync, sum + emit ----
#pragma unroll
  for (int reg = 0; reg < 16; ++reg) {
    const int row = (reg & 3) + 8 * (reg >> 2) + 4 * half;
    Cs[kh * 64 * 36 + (wr * 32 + row) * 36 + l31] = acc[reg];
  }
  __syncthreads();

  {
    const int jl = tid >> 6;                // local j 0..3
    const int b  = tid & 63;                // local b
    const float4 p0 = *(const float4*)&Cs[b * 36 + jl * 8];
    const float4 p1 = *(const float4*)&Cs[b * 36 + jl * 8 + 4];
    const float4 q0 = *(const float4*)&Cs[64 * 36 + b * 36 + jl * 8];
    const float4 q1 = *(const float4*)&Cs[64 * 36 + b * 36 + jl * 8 + 4];
    const float4 m0 = float4{p0.x + q0.x, p0.y + q0.y, p0.z + q0.z, p0.w + q0.w};
    const float4 m1 = float4{p1.x + q1.x, p1.y + q1.y, p1.z + q1.z, p1.w + q1.w};
    const int j_g = blockIdx.y * 4 + jl;
    const int idx = j_g * NB + b0 + b;
    ((float4*)Mp)[idx * 2]     = m0;
    ((float4*)Mp)[idx * 2 + 1] = m1;
    float s = m0.x * m0.x;
    s = fmaf(m0.y, m0.y, s); s = fmaf(m0.z, m0.z, s); s = fmaf(m0.w, m0.w, s);
    s = fmaf(m1.x, m1.x, s); s = fmaf(m1.y, m1.y, s); s = fmaf(m1.z, m1.z, s);
    s = fmaf(m1.w, m1.w, s);
    na[idx] = s;
    uint4 pk;
    pk.x = f2bf(m0.x) | (f2bf(m0.y) << 16);
    pk.y = f2bf(m0.z) | (f2bf(m0.w) << 16);
    pk.z = f2bf(m1.x) | (f2bf(m1.y) << 16);
    pk.w = f2bf(m1.z) | (f2bf(m1.w) << 16);
    Mb[idx] = pk;
  }
}

// ---------------------------------------------------------------------------
// Kernel 2: pairwise — proven structure (1024 blocks, LDS-staged). R11
// change: the 16-way prefilter min is a DEPTH-4 TREE (was a depth-15 linear
// fminf chain = ~75-90cy dependent-latency stall per bt iteration; the tree
// cuts it to ~25cy and exposes v_min3_f32 fusion). min is associative over
// these finite values => flagged pair set, corrections, and output are
// bit-identical to the proven kernel.
// ---------------------------------------------------------------------------
__global__ __launch_bounds__(256) void pairwise_kernel(const uint4* __restrict__ Mb,
                                                       const float* __restrict__ na,
                                                       const float* __restrict__ Mp,
                                                       float* __restrict__ out) {
  const int j    = blockIdx.x;
  const int ag   = blockIdx.y;
  const int bh   = blockIdx.z;
  const int tid  = threadIdx.x;
  const int lane = tid & 63;
  const int w    = tid >> 6;
  const int col  = lane & 31;
  const int h    = lane >> 5;
  const int jb   = j * NB;

  __shared__ uint4 Mb_s[513];    // [512] = zeros for K-pad lanes
  __shared__ float nb_s[512];
  __shared__ float na_s[128];

  const int bbeg = bh * 512;
  Mb_s[tid]       = Mb[jb + bbeg + tid];
  Mb_s[tid + 256] = Mb[jb + bbeg + tid + 256];
  nb_s[tid]       = na[jb + bbeg + tid];
  nb_s[tid + 256] = na[jb + bbeg + tid + 256];
  if (tid == 0) Mb_s[512] = uint4{0u, 0u, 0u, 0u};

  const int a0 = ag * 128 + w * 32;
  if (lane < 32) na_s[w * 32 + lane] = na[jb + a0 + lane];

  uint4 araw = uint4{0u, 0u, 0u, 0u};
  if (lane < 32) araw = Mb[jb + a0 + lane];
  const bf16x8 af = __builtin_bit_cast(bf16x8, araw);

  __syncthreads();

  float c995[16];
#pragma unroll
  for (int reg = 0; reg < 16; ++reg) {
    const int row = (reg & 3) + 8 * (reg >> 2) + 4 * h;
    c995[reg] = 0.995f * na_s[w * 32 + row];
  }

  const floatx16 zero = {};

#pragma unroll 2
  for (int bt = 0; bt < 16; ++bt) {
    const int bidx = bt * 32 + col;
    const uint4 braw = Mb_s[lane < 32 ? bidx : 512];
    const bf16x8 bf = __builtin_bit_cast(bf16x8, braw);
    const floatx16 P = __builtin_amdgcn_mfma_f32_32x32x16_bf16(af, bf, zero, 0, 0, 0);
    const float nb_l = nb_s[bidx];
    const float rhs = 100.0f - 0.995f * nb_l;

    // d[reg] = 0.995*na - 2P  (all independent fmaf); min via depth-4 tree
    float d0  = fmaf(-2.0f, P[0],  c995[0]);
    float d1  = fmaf(-2.0f, P[1],  c995[1]);
    float d2  = fmaf(-2.0f, P[2],  c995[2]);
    float d3  = fmaf(-2.0f, P[3],  c995[3]);
    float d4  = fmaf(-2.0f, P[4],  c995[4]);
    float d5  = fmaf(-2.0f, P[5],  c995[5]);
    float d6  = fmaf(-2.0f, P[6],  c995[6]);
    float d7  = fmaf(-2.0f, P[7],  c995[7]);
    float d8  = fmaf(-2.0f, P[8],  c995[8]);
    float d9  = fmaf(-2.0f, P[9],  c995[9]);
    float d10 = fmaf(-2.0f, P[10], c995[10]);
    float d11 = fmaf(-2.0f, P[11], c995[11]);
    float d12 = fmaf(-2.0f, P[12], c995[12]);
    float d13 = fmaf(-2.0f, P[13], c995[13]);
    float d14 = fmaf(-2.0f, P[14], c995[14]);
    float d15 = fmaf(-2.0f, P[15], c995[15]);
    const float m0 = fminf(fminf(d0, d1), fminf(d2, d3));      // min3-fusable
    const float m1 = fminf(fminf(d4, d5), fminf(d6, d7));
    const float m2 = fminf(fminf(d8, d9), fminf(d10, d11));
    const float m3 = fminf(fminf(d12, d13), fminf(d14, d15));
    const float t = fminf(fminf(m0, m1), fminf(m2, m3));

    if (__any(t < rhs)) {   // rare: ~diagonal tiles only
#pragma unroll
      for (int reg = 0; reg < 16; ++reg) {
        if (fmaf(-2.0f, P[reg], c995[reg]) < rhs) {
          const int row = (reg & 3) + 8 * (reg >> 2) + 4 * h;
          const int a = a0 + row;
          const int b = bbeg + bt * 32 + col;
          float corr;
          if (a == b) {
            corr = 1.0f - EXPN10;
          } else {
            const float4 av0 = ((const float4*)Mp)[(jb + a) * 2];
            const float4 av1 = ((const float4*)Mp)[(jb + a) * 2 + 1];
            const float4 bv0 = ((const float4*)Mp)[(jb + b) * 2];
            const float4 bv1 = ((const float4*)Mp)[(jb + b) * 2 + 1];
            float dd = av0.x - bv0.x; float sq = dd * dd;
            dd = av0.y - bv0.y; sq = fmaf(dd, dd, sq);
            dd = av0.z - bv0.z; sq = fmaf(dd, dd, sq);
            dd = av0.w - bv0.w; sq = fmaf(dd, dd, sq);
            dd = av1.x - bv1.x; sq = fmaf(dd, dd, sq);
            dd = av1.y - bv1.y; sq = fmaf(dd, dd, sq);
            dd = av1.z - bv1.z; sq = fmaf(dd, dd, sq);
            dd = av1.w - bv1.w; sq = fmaf(dd, dd, sq);
            const float nrm = sqrtf(sq);
            corr = (nrm < 10.0f) ? (__expf(-nrm) - EXPN10) : 0.0f;
          }
          if (corr != 0.0f) atomicAdd(&out[a * OUTC + NIN + j], corr);
        }
      }
    }
  }
}

// ---------------------------------------------------------------------------
extern "C" void kernel_launch(void* const* d_in, const int* in_sizes, int n_in,
                              void* d_out, int out_size, void* d_ws, size_t ws_size,
                              hipStream_t stream) {
  const float* x = (const float*)d_in[0];
  const float* T = (const float*)d_in[1];
  float* out = (float*)d_out;

  // workspace layout (3.25 MB)
  float* Mp  = (float*)d_ws;                         // [64][1024][8] fp32   2 MB
  float* na  = Mp + (size_t)NJ * NB * NK;            // [64][1024]         256 KB
  uint4* Mb  = (uint4*)(na + (size_t)NJ * NB);       // [64][1024] bf16x8    1 MB

  gemm_fused<<<dim3(16, 16), 256, 0, stream>>>(x, T, Mp, Mb, na, out);
  pairwise_kernel<<<dim3(NJ, 8, 2), 256, 0, stream>>>(Mb, na, Mp, out);
}

// Round 12
// 69.763 us; speedup vs baseline: 1.0447x; 1.0447x over previous
//
#include <hip/hip_runtime.h>

// Problem constants
constexpr int NB  = 1024;
constexpr int NIN = 512;
constexpr int NJ  = 64;
constexpr int NK  = 8;
constexpr int NC  = NJ * NK;          // 512
constexpr int OUTC = NIN + NJ;        // 576
constexpr float EXPN10 = 4.5399929762484854e-05f;
constexpr float FEAT_BASE = 1024.0f * EXPN10;

typedef __bf16 bf16x8 __attribute__((ext_vector_type(8)));
typedef float floatx16 __attribute__((ext_vector_type(16)));

__device__ __forceinline__ unsigned f2bf(float f) {  // RNE fp32->bf16
  unsigned u = __float_as_uint(f);
  u += 0x7FFFu + ((u >> 16) & 1u);
  return u >> 16;
}

// ---------------------------------------------------------------------------
// Kernel 1 (gemm_fused): byte-identical to R8 (best measured config).
// ---------------------------------------------------------------------------
__global__ __launch_bounds__(256) void gemm_fused(const float* __restrict__ x,
                                                  const float* __restrict__ T,
                                                  float* __restrict__ Mp,
                                                  uint4* __restrict__ Mb,
                                                  float* __restrict__ na,
                                                  float* __restrict__ out) {
  __shared__ __align__(16) ushort smem_u[2 * 64 * 136 + 2 * 32 * 136];  // 52224 B
  ushort* Xs = smem_u;                     // [2][64][136] bf16 A halves
  ushort* Ts = smem_u + 2 * 64 * 136;      // [2][32][136] bf16 B halves (transposed)
  float*  Cs = (float*)smem_u;             // [2][64][36] fp32 partial tiles (overlay)

  const int tid = threadIdx.x;
  const int b0 = blockIdx.x * 64;
  const int c0 = blockIdx.y * 32;

  const int lane = tid & 63;
  const int w    = tid >> 6;
  const int l31  = lane & 31;
  const int half = lane >> 5;
  const int wr   = w & 1;        // arow half
  const int kh   = w >> 1;       // K half owned by this wave
  const int arow = wr * 32 + l31;

  // B-transpose thread mapping
  const int bk = tid >> 3;        // 0..31 : k-pair index within 64-row group
  const int bc = (tid & 7) * 4;   // 0..28 : c-quad offset

  // ---- out init (256 blocks x 576 float4) ----
  const int bidf = blockIdx.y * 16 + blockIdx.x;   // 0..255
#pragma unroll
  for (int it = 0; it < 3; ++it) {
    const int li = it * 256 + tid;
    if (li < 576) {
      const int gi = bidf * 576 + li;
      const int b = gi / (OUTC / 4);                 // /144 -> magic mul
      const int r = gi - b * (OUTC / 4);
      float4 v;
      if (r < NIN / 4) v = ((const float4*)x)[b * (NIN / 4) + r];
      else v = float4{FEAT_BASE, FEAT_BASE, FEAT_BASE, FEAT_BASE};
      ((float4*)out)[gi] = v;
    }
  }

  floatx16 acc = {};

  for (int z = 0; z < 2; ++z) {
    // ======== load phase: ALL global loads for BOTH K-halves batched ========
    float4 av[16];
#pragma unroll
    for (int kk = 0; kk < 2; ++kk) {
#pragma unroll
      for (int t = 0; t < 4; ++t) {
        const int u = t * 256 + tid;
        const int row = u >> 4, seg = u & 15;
        const size_t base = (size_t)(b0 + row) * NIN + (kk * 2 + z) * 128 + seg * 8;
        av[kk * 8 + 2 * t]     = *(const float4*)&x[base];
        av[kk * 8 + 2 * t + 1] = *(const float4*)&x[base + 4];
      }
    }
    float4 bv[8];
#pragma unroll
    for (int kk = 0; kk < 2; ++kk) {
#pragma unroll
      for (int it = 0; it < 2; ++it) {
        const int k0 = it * 64 + bk * 2;             // local k (even), 0..126
        const size_t base = (size_t)((kk * 2 + z) * 128 + k0) * NC + c0 + bc;
        bv[kk * 4 + 2 * it]     = *(const float4*)&T[base];      // row k0
        bv[kk * 4 + 2 * it + 1] = *(const float4*)&T[base + NC]; // row k0+1
      }
    }

    // ======== write phase: convert + LDS ========
#pragma unroll
    for (int kk = 0; kk < 2; ++kk) {
#pragma unroll
      for (int t = 0; t < 4; ++t) {
        const int u = t * 256 + tid;
        const int row = u >> 4, seg = u & 15;
        uint4 p;
        p.x = f2bf(av[kk * 8 + 2 * t].x) | (f2bf(av[kk * 8 + 2 * t].y) << 16);
        p.y = f2bf(av[kk * 8 + 2 * t].z) | (f2bf(av[kk * 8 + 2 * t].w) << 16);
        p.z = f2bf(av[kk * 8 + 2 * t + 1].x) | (f2bf(av[kk * 8 + 2 * t + 1].y) << 16);
        p.w = f2bf(av[kk * 8 + 2 * t + 1].z) | (f2bf(av[kk * 8 + 2 * t + 1].w) << 16);
        *(uint4*)&Xs[kk * 64 * 136 + row * 136 + seg * 8] = p;
      }
      unsigned* Tw = (unsigned*)(Ts + kk * 32 * 136);   // dword view, row stride 68
#pragma unroll
      for (int it = 0; it < 2; ++it) {
        const float* lo = &bv[kk * 4 + 2 * it].x;
        const float* hi = &bv[kk * 4 + 2 * it + 1].x;
#pragma unroll
        for (int q = 0; q < 4; ++q) {
          const unsigned val = f2bf(lo[q]) | (f2bf(hi[q]) << 16);
          Tw[(bc + q) * 68 + it * 32 + bk] = val;      // Ts[kk][c][k0..k0+1]
        }
      }
    }

    __syncthreads();

    // ---- MFMA: 8 steps of K=16 on this wave's K-half ----
#pragma unroll
    for (int s = 0; s < 8; ++s) {
      const bf16x8 af = *(const bf16x8*)&Xs[kh * 64 * 136 + arow * 136 + s * 16 + half * 8];
      const bf16x8 bf = *(const bf16x8*)&Ts[kh * 32 * 136 + l31 * 136 + s * 16 + half * 8];
      acc = __builtin_amdgcn_mfma_f32_32x32x16_bf16(af, bf, acc, 0, 0, 0);
    }
    __syncthreads();
  }

  // ---- epilogue: partials -> Cs[kh], sync, sum + emit ----
#pragma unroll
  for (int reg = 0; reg < 16; ++reg) {
    const int row = (reg & 3) + 8 * (reg >> 2) + 4 * half;
    Cs[kh * 64 * 36 + (wr * 32 + row) * 36 + l31] = acc[reg];
  }
  __syncthreads();

  {
    const int jl = tid >> 6;                // local j 0..3
    const int b  = tid & 63;                // local b
    const float4 p0 = *(const float4*)&Cs[b * 36 + jl * 8];
    const float4 p1 = *(const float4*)&Cs[b * 36 + jl * 8 + 4];
    const float4 q0 = *(const float4*)&Cs[64 * 36 + b * 36 + jl * 8];
    const float4 q1 = *(const float4*)&Cs[64 * 36 + b * 36 + jl * 8 + 4];
    const float4 m0 = float4{p0.x + q0.x, p0.y + q0.y, p0.z + q0.z, p0.w + q0.w};
    const float4 m1 = float4{p1.x + q1.x, p1.y + q1.y, p1.z + q1.z, p1.w + q1.w};
    const int j_g = blockIdx.y * 4 + jl;
    const int idx = j_g * NB + b0 + b;
    ((float4*)Mp)[idx * 2]     = m0;
    ((float4*)Mp)[idx * 2 + 1] = m1;
    float s = m0.x * m0.x;
    s = fmaf(m0.y, m0.y, s); s = fmaf(m0.z, m0.z, s); s = fmaf(m0.w, m0.w, s);
    s = fmaf(m1.x, m1.x, s); s = fmaf(m1.y, m1.y, s); s = fmaf(m1.z, m1.z, s);
    s = fmaf(m1.w, m1.w, s);
    na[idx] = s;
    uint4 pk;
    pk.x = f2bf(m0.x) | (f2bf(m0.y) << 16);
    pk.y = f2bf(m0.z) | (f2bf(m0.w) << 16);
    pk.z = f2bf(m1.x) | (f2bf(m1.y) << 16);
    pk.w = f2bf(m1.z) | (f2bf(m1.w) << 16);
    Mb[idx] = pk;
  }
}

// ---------------------------------------------------------------------------
// Kernel 2: pairwise R12 — SYMMETRY HALVING. c(a,b)=c(b,a), so sweep only
// unordered tile pairs: 8x8 tiles of 128 rows -> 36 pairs (ta<=tb) x 64 j
// = 2304 blocks. Diagonal tiles (ta==tb): full square, original single-
// atomic semantics (covers a==b and both orders of within-tile pairs).
// Off-diagonal: each unordered pair computed ONCE; flagged corrections
// scatter to BOTH out[a][j] and out[b][j] (corr is symmetric -> identical
// sum). MFMA count 65536 -> 36864 (0.56x); prefilter VALU likewise.
// Prefilter constants / flag condition / correction math unchanged.
// ---------------------------------------------------------------------------
__global__ __launch_bounds__(256) void pairwise_kernel(const uint4* __restrict__ Mb,
                                                       const float* __restrict__ na,
                                                       const float* __restrict__ Mp,
                                                       float* __restrict__ out) {
  const int j = blockIdx.x;
  int tp = blockIdx.y;              // 0..35 -> (ta, tb), ta<=tb
  int ta = 0;
  while (tp >= 8 - ta) { tp -= 8 - ta; ++ta; }
  const int tb = ta + tp;
  const bool offd = (ta != tb);

  const int tid  = threadIdx.x;
  const int lane = tid & 63;
  const int w    = tid >> 6;
  const int col  = lane & 31;
  const int h    = lane >> 5;
  const int jb   = j * NB;

  __shared__ uint4 Mb_s[129];    // [128] = zeros for K-pad lanes
  __shared__ float nb_s[128];
  __shared__ float na_s[128];

  const int bbeg = tb * 128;
  if (tid < 128) {
    Mb_s[tid] = Mb[jb + bbeg + tid];
    nb_s[tid] = na[jb + bbeg + tid];
  }
  if (tid == 0) Mb_s[128] = uint4{0u, 0u, 0u, 0u};

  const int a0 = ta * 128 + w * 32;
  if (lane < 32) na_s[w * 32 + lane] = na[jb + a0 + lane];

  uint4 araw = uint4{0u, 0u, 0u, 0u};
  if (lane < 32) araw = Mb[jb + a0 + lane];
  const bf16x8 af = __builtin_bit_cast(bf16x8, araw);

  __syncthreads();

  float c995[16];
#pragma unroll
  for (int reg = 0; reg < 16; ++reg) {
    const int row = (reg & 3) + 8 * (reg >> 2) + 4 * h;
    c995[reg] = 0.995f * na_s[w * 32 + row];
  }

  const floatx16 zero = {};

#pragma unroll
  for (int bt = 0; bt < 4; ++bt) {
    const int bidx = bt * 32 + col;
    const uint4 braw = Mb_s[lane < 32 ? bidx : 128];
    const bf16x8 bf = __builtin_bit_cast(bf16x8, braw);
    const floatx16 P = __builtin_amdgcn_mfma_f32_32x32x16_bf16(af, bf, zero, 0, 0, 0);
    const float nb_l = nb_s[bidx];
    const float rhs = 100.0f - 0.995f * nb_l;

    // d[reg] = 0.995*na - 2P (independent fmaf); min via depth-4 tree
    float d0  = fmaf(-2.0f, P[0],  c995[0]);
    float d1  = fmaf(-2.0f, P[1],  c995[1]);
    float d2  = fmaf(-2.0f, P[2],  c995[2]);
    float d3  = fmaf(-2.0f, P[3],  c995[3]);
    float d4  = fmaf(-2.0f, P[4],  c995[4]);
    float d5  = fmaf(-2.0f, P[5],  c995[5]);
    float d6  = fmaf(-2.0f, P[6],  c995[6]);
    float d7  = fmaf(-2.0f, P[7],  c995[7]);
    float d8  = fmaf(-2.0f, P[8],  c995[8]);
    float d9  = fmaf(-2.0f, P[9],  c995[9]);
    float d10 = fmaf(-2.0f, P[10], c995[10]);
    float d11 = fmaf(-2.0f, P[11], c995[11]);
    float d12 = fmaf(-2.0f, P[12], c995[12]);
    float d13 = fmaf(-2.0f, P[13], c995[13]);
    float d14 = fmaf(-2.0f, P[14], c995[14]);
    float d15 = fmaf(-2.0f, P[15], c995[15]);
    const float m0 = fminf(fminf(d0, d1), fminf(d2, d3));
    const float m1 = fminf(fminf(d4, d5), fminf(d6, d7));
    const float m2 = fminf(fminf(d8, d9), fminf(d10, d11));
    const float m3 = fminf(fminf(d12, d13), fminf(d14, d15));
    const float t = fminf(fminf(m0, m1), fminf(m2, m3));

    if (__any(t < rhs)) {   // rare: diagonal tiles + ~1e-5 FP rate
#pragma unroll
      for (int reg = 0; reg < 16; ++reg) {
        if (fmaf(-2.0f, P[reg], c995[reg]) < rhs) {
          const int row = (reg & 3) + 8 * (reg >> 2) + 4 * h;
          const int a = a0 + row;
          const int b = bbeg + bt * 32 + col;
          float corr;
          if (a == b) {
            corr = 1.0f - EXPN10;
          } else {
            const float4 av0 = ((const float4*)Mp)[(jb + a) * 2];
            const float4 av1 = ((const float4*)Mp)[(jb + a) * 2 + 1];
            const float4 bv0 = ((const float4*)Mp)[(jb + b) * 2];
            const float4 bv1 = ((const float4*)Mp)[(jb + b) * 2 + 1];
            float dd = av0.x - bv0.x; float sq = dd * dd;
            dd = av0.y - bv0.y; sq = fmaf(dd, dd, sq);
            dd = av0.z - bv0.z; sq = fmaf(dd, dd, sq);
            dd = av0.w - bv0.w; sq = fmaf(dd, dd, sq);
            dd = av1.x - bv1.x; sq = fmaf(dd, dd, sq);
            dd = av1.y - bv1.y; sq = fmaf(dd, dd, sq);
            dd = av1.z - bv1.z; sq = fmaf(dd, dd, sq);
            dd = av1.w - bv1.w; sq = fmaf(dd, dd, sq);
            const float nrm = sqrtf(sq);
            corr = (nrm < 10.0f) ? (__expf(-nrm) - EXPN10) : 0.0f;
          }
          if (corr != 0.0f) {
            atomicAdd(&out[a * OUTC + NIN + j], corr);
            if (offd) atomicAdd(&out[b * OUTC + NIN + j], corr);
          }
        }
      }
    }
  }
}

// ---------------------------------------------------------------------------
extern "C" void kernel_launch(void* const* d_in, const int* in_sizes, int n_in,
                              void* d_out, int out_size, void* d_ws, size_t ws_size,
                              hipStream_t stream) {
  const float* x = (const float*)d_in[0];
  const float* T = (const float*)d_in[1];
  float* out = (float*)d_out;

  // workspace layout (3.25 MB)
  float* Mp  = (float*)d_ws;                         // [64][1024][8] fp32   2 MB
  float* na  = Mp + (size_t)NJ * NB * NK;            // [64][1024]         256 KB
  uint4* Mb  = (uint4*)(na + (size_t)NJ * NB);       // [64][1024] bf16x8    1 MB

  gemm_fused<<<dim3(16, 16), 256, 0, stream>>>(x, T, Mp, Mb, na, out);
  pairwise_kernel<<<dim3(NJ, 36), 256, 0, stream>>>(Mb, na, Mp, out);
}

// Round 13
// 69.163 us; speedup vs baseline: 1.0538x; 1.0087x over previous
//
#include <hip/hip_runtime.h>

// Problem constants
constexpr int NB  = 1024;
constexpr int NIN = 512;
constexpr int NJ  = 64;
constexpr int NK  = 8;
constexpr int NC  = NJ * NK;          // 512
constexpr int OUTC = NIN + NJ;        // 576
constexpr float EXPN10 = 4.5399929762484854e-05f;
constexpr float FEAT_BASE = 1024.0f * EXPN10;

typedef __bf16 bf16x8 __attribute__((ext_vector_type(8)));
typedef float floatx16 __attribute__((ext_vector_type(16)));

__device__ __forceinline__ unsigned f2bf(float f) {  // RNE fp32->bf16
  unsigned u = __float_as_uint(f);
  u += 0x7FFFu + ((u >> 16) & 1u);
  return u >> 16;
}

// ---------------------------------------------------------------------------
// Kernel 1 (gemm_fused): byte-identical to R8 (best measured config).
// XCD note: natural mapping bid=bx+16*by gives xcd=bx%8 -> all blocks
// sharing an x-row slice (b0) already land on the same XCD; x-reuse is
// already L2-local. Left untouched.
// ---------------------------------------------------------------------------
__global__ __launch_bounds__(256) void gemm_fused(const float* __restrict__ x,
                                                  const float* __restrict__ T,
                                                  float* __restrict__ Mp,
                                                  uint4* __restrict__ Mb,
                                                  float* __restrict__ na,
                                                  float* __restrict__ out) {
  __shared__ __align__(16) ushort smem_u[2 * 64 * 136 + 2 * 32 * 136];  // 52224 B
  ushort* Xs = smem_u;                     // [2][64][136] bf16 A halves
  ushort* Ts = smem_u + 2 * 64 * 136;      // [2][32][136] bf16 B halves (transposed)
  float*  Cs = (float*)smem_u;             // [2][64][36] fp32 partial tiles (overlay)

  const int tid = threadIdx.x;
  const int b0 = blockIdx.x * 64;
  const int c0 = blockIdx.y * 32;

  const int lane = tid & 63;
  const int w    = tid >> 6;
  const int l31  = lane & 31;
  const int half = lane >> 5;
  const int wr   = w & 1;        // arow half
  const int kh   = w >> 1;       // K half owned by this wave
  const int arow = wr * 32 + l31;

  // B-transpose thread mapping
  const int bk = tid >> 3;        // 0..31 : k-pair index within 64-row group
  const int bc = (tid & 7) * 4;   // 0..28 : c-quad offset

  // ---- out init (256 blocks x 576 float4) ----
  const int bidf = blockIdx.y * 16 + blockIdx.x;   // 0..255
#pragma unroll
  for (int it = 0; it < 3; ++it) {
    const int li = it * 256 + tid;
    if (li < 576) {
      const int gi = bidf * 576 + li;
      const int b = gi / (OUTC / 4);                 // /144 -> magic mul
      const int r = gi - b * (OUTC / 4);
      float4 v;
      if (r < NIN / 4) v = ((const float4*)x)[b * (NIN / 4) + r];
      else v = float4{FEAT_BASE, FEAT_BASE, FEAT_BASE, FEAT_BASE};
      ((float4*)out)[gi] = v;
    }
  }

  floatx16 acc = {};

  for (int z = 0; z < 2; ++z) {
    // ======== load phase: ALL global loads for BOTH K-halves batched ========
    float4 av[16];
#pragma unroll
    for (int kk = 0; kk < 2; ++kk) {
#pragma unroll
      for (int t = 0; t < 4; ++t) {
        const int u = t * 256 + tid;
        const int row = u >> 4, seg = u & 15;
        const size_t base = (size_t)(b0 + row) * NIN + (kk * 2 + z) * 128 + seg * 8;
        av[kk * 8 + 2 * t]     = *(const float4*)&x[base];
        av[kk * 8 + 2 * t + 1] = *(const float4*)&x[base + 4];
      }
    }
    float4 bv[8];
#pragma unroll
    for (int kk = 0; kk < 2; ++kk) {
#pragma unroll
      for (int it = 0; it < 2; ++it) {
        const int k0 = it * 64 + bk * 2;             // local k (even), 0..126
        const size_t base = (size_t)((kk * 2 + z) * 128 + k0) * NC + c0 + bc;
        bv[kk * 4 + 2 * it]     = *(const float4*)&T[base];      // row k0
        bv[kk * 4 + 2 * it + 1] = *(const float4*)&T[base + NC]; // row k0+1
      }
    }

    // ======== write phase: convert + LDS ========
#pragma unroll
    for (int kk = 0; kk < 2; ++kk) {
#pragma unroll
      for (int t = 0; t < 4; ++t) {
        const int u = t * 256 + tid;
        const int row = u >> 4, seg = u & 15;
        uint4 p;
        p.x = f2bf(av[kk * 8 + 2 * t].x) | (f2bf(av[kk * 8 + 2 * t].y) << 16);
        p.y = f2bf(av[kk * 8 + 2 * t].z) | (f2bf(av[kk * 8 + 2 * t].w) << 16);
        p.z = f2bf(av[kk * 8 + 2 * t + 1].x) | (f2bf(av[kk * 8 + 2 * t + 1].y) << 16);
        p.w = f2bf(av[kk * 8 + 2 * t + 1].z) | (f2bf(av[kk * 8 + 2 * t + 1].w) << 16);
        *(uint4*)&Xs[kk * 64 * 136 + row * 136 + seg * 8] = p;
      }
      unsigned* Tw = (unsigned*)(Ts + kk * 32 * 136);   // dword view, row stride 68
#pragma unroll
      for (int it = 0; it < 2; ++it) {
        const float* lo = &bv[kk * 4 + 2 * it].x;
        const float* hi = &bv[kk * 4 + 2 * it + 1].x;
#pragma unroll
        for (int q = 0; q < 4; ++q) {
          const unsigned val = f2bf(lo[q]) | (f2bf(hi[q]) << 16);
          Tw[(bc + q) * 68 + it * 32 + bk] = val;      // Ts[kk][c][k0..k0+1]
        }
      }
    }

    __syncthreads();

    // ---- MFMA: 8 steps of K=16 on this wave's K-half ----
#pragma unroll
    for (int s = 0; s < 8; ++s) {
      const bf16x8 af = *(const bf16x8*)&Xs[kh * 64 * 136 + arow * 136 + s * 16 + half * 8];
      const bf16x8 bf = *(const bf16x8*)&Ts[kh * 32 * 136 + l31 * 136 + s * 16 + half * 8];
      acc = __builtin_amdgcn_mfma_f32_32x32x16_bf16(af, bf, acc, 0, 0, 0);
    }
    __syncthreads();
  }

  // ---- epilogue: partials -> Cs[kh], sync, sum + emit ----
#pragma unroll
  for (int reg = 0; reg < 16; ++reg) {
    const int row = (reg & 3) + 8 * (reg >> 2) + 4 * half;
    Cs[kh * 64 * 36 + (wr * 32 + row) * 36 + l31] = acc[reg];
  }
  __syncthreads();

  {
    const int jl = tid >> 6;                // local j 0..3
    const int b  = tid & 63;                // local b
    const float4 p0 = *(const float4*)&Cs[b * 36 + jl * 8];
    const float4 p1 = *(const float4*)&Cs[b * 36 + jl * 8 + 4];
    const float4 q0 = *(const float4*)&Cs[64 * 36 + b * 36 + jl * 8];
    const float4 q1 = *(const float4*)&Cs[64 * 36 + b * 36 + jl * 8 + 4];
    const float4 m0 = float4{p0.x + q0.x, p0.y + q0.y, p0.z + q0.z, p0.w + q0.w};
    const float4 m1 = float4{p1.x + q1.x, p1.y + q1.y, p1.z + q1.z, p1.w + q1.w};
    const int j_g = blockIdx.y * 4 + jl;
    const int idx = j_g * NB + b0 + b;
    ((float4*)Mp)[idx * 2]     = m0;
    ((float4*)Mp)[idx * 2 + 1] = m1;
    float s = m0.x * m0.x;
    s = fmaf(m0.y, m0.y, s); s = fmaf(m0.z, m0.z, s); s = fmaf(m0.w, m0.w, s);
    s = fmaf(m1.x, m1.x, s); s = fmaf(m1.y, m1.y, s); s = fmaf(m1.z, m1.z, s);
    s = fmaf(m1.w, m1.w, s);
    na[idx] = s;
    uint4 pk;
    pk.x = f2bf(m0.x) | (f2bf(m0.y) << 16);
    pk.y = f2bf(m0.z) | (f2bf(m0.w) << 16);
    pk.z = f2bf(m1.x) | (f2bf(m1.y) << 16);
    pk.w = f2bf(m1.z) | (f2bf(m1.w) << 16);
    Mb[idx] = pk;
  }
}

// ---------------------------------------------------------------------------
// Kernel 2: pairwise R13 = R12 symmetry-halved body + XCD-locality swizzle.
// 1-D grid of 2304; decode so all 36 tile-pair blocks of a given j land on
// one XCD slot (xcd = bid%8 heuristic): j = (bid&7)*8 + ((bid>>3)&7),
// tp = bid>>6. Per-XCD working set = 8 j-slices x 52KB = 416KB -> L2
// resident; staging reads become local-L2 (~200cy) instead of remote
// L3/HBM (~500-900cy). Pure relabeling: same blocks, same pair coverage,
// numerics byte-identical to R12.
// ---------------------------------------------------------------------------
__global__ __launch_bounds__(256) void pairwise_kernel(const uint4* __restrict__ Mb,
                                                       const float* __restrict__ na,
                                                       const float* __restrict__ Mp,
                                                       float* __restrict__ out) {
  const int bid = blockIdx.x;
  const int j   = (bid & 7) * 8 + ((bid >> 3) & 7);   // 0..63, XCD-grouped
  int tp = bid >> 6;                 // 0..35 -> (ta, tb), ta<=tb
  int ta = 0;
  while (tp >= 8 - ta) { tp -= 8 - ta; ++ta; }
  const int tb = ta + tp;
  const bool offd = (ta != tb);

  const int tid  = threadIdx.x;
  const int lane = tid & 63;
  const int w    = tid >> 6;
  const int col  = lane & 31;
  const int h    = lane >> 5;
  const int jb   = j * NB;

  __shared__ uint4 Mb_s[129];    // [128] = zeros for K-pad lanes
  __shared__ float nb_s[128];
  __shared__ float na_s[128];

  const int bbeg = tb * 128;
  if (tid < 128) {
    Mb_s[tid] = Mb[jb + bbeg + tid];
    nb_s[tid] = na[jb + bbeg + tid];
  }
  if (tid == 0) Mb_s[128] = uint4{0u, 0u, 0u, 0u};

  const int a0 = ta * 128 + w * 32;
  if (lane < 32) na_s[w * 32 + lane] = na[jb + a0 + lane];

  uint4 araw = uint4{0u, 0u, 0u, 0u};
  if (lane < 32) araw = Mb[jb + a0 + lane];
  const bf16x8 af = __builtin_bit_cast(bf16x8, araw);

  __syncthreads();

  float c995[16];
#pragma unroll
  for (int reg = 0; reg < 16; ++reg) {
    const int row = (reg & 3) + 8 * (reg >> 2) + 4 * h;
    c995[reg] = 0.995f * na_s[w * 32 + row];
  }

  const floatx16 zero = {};

#pragma unroll
  for (int bt = 0; bt < 4; ++bt) {
    const int bidx = bt * 32 + col;
    const uint4 braw = Mb_s[lane < 32 ? bidx : 128];
    const bf16x8 bf = __builtin_bit_cast(bf16x8, braw);
    const floatx16 P = __builtin_amdgcn_mfma_f32_32x32x16_bf16(af, bf, zero, 0, 0, 0);
    const float nb_l = nb_s[bidx];
    const float rhs = 100.0f - 0.995f * nb_l;

    // d[reg] = 0.995*na - 2P (independent fmaf); min via depth-4 tree
    float d0  = fmaf(-2.0f, P[0],  c995[0]);
    float d1  = fmaf(-2.0f, P[1],  c995[1]);
    float d2  = fmaf(-2.0f, P[2],  c995[2]);
    float d3  = fmaf(-2.0f, P[3],  c995[3]);
    float d4  = fmaf(-2.0f, P[4],  c995[4]);
    float d5  = fmaf(-2.0f, P[5],  c995[5]);
    float d6  = fmaf(-2.0f, P[6],  c995[6]);
    float d7  = fmaf(-2.0f, P[7],  c995[7]);
    float d8  = fmaf(-2.0f, P[8],  c995[8]);
    float d9  = fmaf(-2.0f, P[9],  c995[9]);
    float d10 = fmaf(-2.0f, P[10], c995[10]);
    float d11 = fmaf(-2.0f, P[11], c995[11]);
    float d12 = fmaf(-2.0f, P[12], c995[12]);
    float d13 = fmaf(-2.0f, P[13], c995[13]);
    float d14 = fmaf(-2.0f, P[14], c995[14]);
    float d15 = fmaf(-2.0f, P[15], c995[15]);
    const float m0 = fminf(fminf(d0, d1), fminf(d2, d3));
    const float m1 = fminf(fminf(d4, d5), fminf(d6, d7));
    const float m2 = fminf(fminf(d8, d9), fminf(d10, d11));
    const float m3 = fminf(fminf(d12, d13), fminf(d14, d15));
    const float t = fminf(fminf(m0, m1), fminf(m2, m3));

    if (__any(t < rhs)) {   // rare: diagonal tiles + ~1e-5 FP rate
#pragma unroll
      for (int reg = 0; reg < 16; ++reg) {
        if (fmaf(-2.0f, P[reg], c995[reg]) < rhs) {
          const int row = (reg & 3) + 8 * (reg >> 2) + 4 * h;
          const int a = a0 + row;
          const int b = bbeg + bt * 32 + col;
          float corr;
          if (a == b) {
            corr = 1.0f - EXPN10;
          } else {
            const float4 av0 = ((const float4*)Mp)[(jb + a) * 2];
            const float4 av1 = ((const float4*)Mp)[(jb + a) * 2 + 1];
            const float4 bv0 = ((const float4*)Mp)[(jb + b) * 2];
            const float4 bv1 = ((const float4*)Mp)[(jb + b) * 2 + 1];
            float dd = av0.x - bv0.x; float sq = dd * dd;
            dd = av0.y - bv0.y; sq = fmaf(dd, dd, sq);
            dd = av0.z - bv0.z; sq = fmaf(dd, dd, sq);
            dd = av0.w - bv0.w; sq = fmaf(dd, dd, sq);
            dd = av1.x - bv1.x; sq = fmaf(dd, dd, sq);
            dd = av1.y - bv1.y; sq = fmaf(dd, dd, sq);
            dd = av1.z - bv1.z; sq = fmaf(dd, dd, sq);
            dd = av1.w - bv1.w; sq = fmaf(dd, dd, sq);
            const float nrm = sqrtf(sq);
            corr = (nrm < 10.0f) ? (__expf(-nrm) - EXPN10) : 0.0f;
          }
          if (corr != 0.0f) {
            atomicAdd(&out[a * OUTC + NIN + j], corr);
            if (offd) atomicAdd(&out[b * OUTC + NIN + j], corr);
          }
        }
      }
    }
  }
}

// ---------------------------------------------------------------------------
extern "C" void kernel_launch(void* const* d_in, const int* in_sizes, int n_in,
                              void* d_out, int out_size, void* d_ws, size_t ws_size,
                              hipStream_t stream) {
  const float* x = (const float*)d_in[0];
  const float* T = (const float*)d_in[1];
  float* out = (float*)d_out;

  // workspace layout (3.25 MB)
  float* Mp  = (float*)d_ws;                         // [64][1024][8] fp32   2 MB
  float* na  = Mp + (size_t)NJ * NB * NK;            // [64][1024]         256 KB
  uint4* Mb  = (uint4*)(na + (size_t)NJ * NB);       // [64][1024] bf16x8    1 MB

  gemm_fused<<<dim3(16, 16), 256, 0, stream>>>(x, T, Mp, Mb, na, out);
  pairwise_kernel<<<dim3(NJ * 36), 256, 0, stream>>>(Mb, na, Mp, out);
}